// Round 9
// baseline (1271.967 us; speedup 1.0000x reference)
//
#include <hip/hip_runtime.h>
#include <hip/hip_bf16.h>
#include <stdint.h>

// Problem constants
#define TT 4
#define BE 16
#define BB 64          // TT * BE
#define CC 512
#define NN 512
#define NH 8
#define GD 64          // CC / NH
#define NW 16          // NN/32 packed words per (b,c) row
#define TAU 0.5f
#define THRESH 1.0f
#define SCALE 0.125f
#define EPS 1e-5f

// ---------------------------------------------------------------------------
// Kernel 1: 1x1-conv + BN + LIF over T -> bit-packed spikes.
// z = w*BE + be (w=0,1,2 selects q/k/v). Tile 64c x 128n, micro 4x8.
// 2-deep software pipeline: register prefetch + double-buffered LDS,
// ONE barrier per K-step (no vmcnt(0) drain on the critical path).
// ---------------------------------------------------------------------------
__global__ __launch_bounds__(256) void conv_bn_lif_kernel(
    const float* __restrict__ x,      // [BB, CC, NN]
    const float* __restrict__ Wq,     // [CC, CC] (out, in)
    const float* __restrict__ Wk,
    const float* __restrict__ Wv,
    const float* __restrict__ bn_g,   // [4, CC]
    const float* __restrict__ bn_b,
    const float* __restrict__ bn_m,
    const float* __restrict__ bn_v,
    uint32_t* __restrict__ qp,        // [BB*CC, NW] packed
    uint32_t* __restrict__ kp,
    uint32_t* __restrict__ vp)
{
    __shared__ float Xs[2][16][132];
    __shared__ float Ws_s[2][16][68];

    const int tid = threadIdx.x;
    const int tx = tid & 15;
    const int ty = tid >> 4;
    const int n0 = blockIdx.x * 128;
    const int c0 = blockIdx.y * 64;
    const int z  = blockIdx.z;
    const int be = z & (BE - 1);
    const int w  = z >> 4;

    const float* W = (w == 0) ? Wq : (w == 1) ? Wk : Wv;
    uint32_t* outp = (w == 0) ? qp : (w == 1) ? kp : vp;

    float inv_c[4], add_c[4];
#pragma unroll
    for (int i = 0; i < 4; ++i) {
        int c = c0 + 4 * ty + i;
        float g = bn_g[w * CC + c];
        float b = bn_b[w * CC + c];
        float m = bn_m[w * CC + c];
        float v = bn_v[w * CC + c];
        float inv = g / sqrtf(v + EPS);
        inv_c[i] = inv;
        add_c[i] = b - m * inv;
    }

    // staging maps
    const int xkk0 = tid >> 5;          // f = tid      -> kk, colf
    const int xcf0 = tid & 31;
    const int xkk1 = (tid + 256) >> 5;  // f = tid+256
    const int xcf1 = (tid + 256) & 31;
    const int wr = tid >> 2;
    const int wkw = tid & 3;

    float mem[4][8];
#pragma unroll
    for (int i = 0; i < 4; ++i)
#pragma unroll
        for (int j = 0; j < 8; ++j) mem[i][j] = 0.0f;

    for (int t = 0; t < TT; ++t) {
        const int b = t * BE + be;
        const float* xb = x + (size_t)b * CC * NN;

        float acc[4][8];
#pragma unroll
        for (int i = 0; i < 4; ++i)
#pragma unroll
            for (int j = 0; j < 8; ++j) acc[i][j] = 0.0f;

        // ---- prologue: k0 = 0 -> buf 0
        float4 px0 = *(const float4*)&xb[(size_t)(0 + xkk0) * NN + n0 + 4 * xcf0];
        float4 px1 = *(const float4*)&xb[(size_t)(0 + xkk1) * NN + n0 + 4 * xcf1];
        float4 pw  = *(const float4*)&W[(size_t)(c0 + wr) * CC + 0 + 4 * wkw];
        *(float4*)&Xs[0][xkk0][4 * xcf0] = px0;
        *(float4*)&Xs[0][xkk1][4 * xcf1] = px1;
        Ws_s[0][4 * wkw + 0][wr] = pw.x;
        Ws_s[0][4 * wkw + 1][wr] = pw.y;
        Ws_s[0][4 * wkw + 2][wr] = pw.z;
        Ws_s[0][4 * wkw + 3][wr] = pw.w;
        __syncthreads();
        // prefetch k0 = 16
        px0 = *(const float4*)&xb[(size_t)(16 + xkk0) * NN + n0 + 4 * xcf0];
        px1 = *(const float4*)&xb[(size_t)(16 + xkk1) * NN + n0 + 4 * xcf1];
        pw  = *(const float4*)&W[(size_t)(c0 + wr) * CC + 16 + 4 * wkw];

        int cur = 0;
        for (int k0 = 0; k0 < CC; k0 += 16) {
#pragma unroll
            for (int kk = 0; kk < 16; ++kk) {
                float4 av  = *(float4*)&Ws_s[cur][kk][4 * ty];
                float4 xlo = *(float4*)&Xs[cur][kk][4 * tx];
                float4 xhi = *(float4*)&Xs[cur][kk][64 + 4 * tx];
                const float a[4] = {av.x, av.y, av.z, av.w};
                const float xl[4] = {xlo.x, xlo.y, xlo.z, xlo.w};
                const float xh[4] = {xhi.x, xhi.y, xhi.z, xhi.w};
#pragma unroll
                for (int i = 0; i < 4; ++i) {
#pragma unroll
                    for (int j = 0; j < 4; ++j) {
                        acc[i][j] += a[i] * xl[j];
                        acc[i][4 + j] += a[i] * xh[j];
                    }
                }
            }
            if (k0 + 16 < CC) {
                int nxt = cur ^ 1;
                *(float4*)&Xs[nxt][xkk0][4 * xcf0] = px0;
                *(float4*)&Xs[nxt][xkk1][4 * xcf1] = px1;
                Ws_s[nxt][4 * wkw + 0][wr] = pw.x;
                Ws_s[nxt][4 * wkw + 1][wr] = pw.y;
                Ws_s[nxt][4 * wkw + 2][wr] = pw.z;
                Ws_s[nxt][4 * wkw + 3][wr] = pw.w;
                __syncthreads();
                cur = nxt;
                if (k0 + 32 < CC) {
                    int kn = k0 + 32;
                    px0 = *(const float4*)&xb[(size_t)(kn + xkk0) * NN + n0 + 4 * xcf0];
                    px1 = *(const float4*)&xb[(size_t)(kn + xkk1) * NN + n0 + 4 * xcf1];
                    pw  = *(const float4*)&W[(size_t)(c0 + wr) * CC + kn + 4 * wkw];
                }
            }
        }

        // epilogue: BN + LIF -> nibbles -> octet shfl-OR -> packed words
#pragma unroll
        for (int i = 0; i < 4; ++i) {
            uint32_t nibLo = 0, nibHi = 0;
#pragma unroll
            for (int j = 0; j < 4; ++j) {
                float y = acc[i][j] * inv_c[i] + add_c[i];
                float m2 = mem[i][j] * TAU + y;
                bool s = m2 > THRESH;
                nibLo |= (s ? 1u : 0u) << j;
                mem[i][j] = s ? 0.0f : m2;

                float y2 = acc[i][4 + j] * inv_c[i] + add_c[i];
                float m22 = mem[i][4 + j] * TAU + y2;
                bool s2 = m22 > THRESH;
                nibHi |= (s2 ? 1u : 0u) << j;
                mem[i][4 + j] = s2 ? 0.0f : m22;
            }
            const size_t rowbase = (size_t)(b * CC + c0 + 4 * ty + i) * NW + (n0 >> 5);
            uint32_t wlo = nibLo << (4 * (tx & 7));
            wlo |= (uint32_t)__shfl_xor((int)wlo, 1);
            wlo |= (uint32_t)__shfl_xor((int)wlo, 2);
            wlo |= (uint32_t)__shfl_xor((int)wlo, 4);
            uint32_t whi = nibHi << (4 * (tx & 7));
            whi |= (uint32_t)__shfl_xor((int)whi, 1);
            whi |= (uint32_t)__shfl_xor((int)whi, 2);
            whi |= (uint32_t)__shfl_xor((int)whi, 4);
            if ((tx & 7) == 0) {
                outp[rowbase + (tx >> 3)] = wlo;
                outp[rowbase + 2 + (tx >> 3)] = whi;
            }
        }
        // next t's prologue writes buf0: safe — last buf0 read (k0=480) is
        // behind the k0=480 barrier; final compute uses buf1 only.
    }
}

// ---------------------------------------------------------------------------
// Kernel 2: fused attention + LIF3 on packed spikes (unchanged, verified).
// ---------------------------------------------------------------------------
__global__ __launch_bounds__(256) void attn_lif_kernel(
    const uint32_t* __restrict__ qp,
    const uint32_t* __restrict__ kp,
    const uint32_t* __restrict__ vp,
    uint32_t* __restrict__ s3p)
{
    __shared__ uint32_t kL[64][NW + 1];
    __shared__ uint32_t vL[64][NW + 1];
    __shared__ float    Msh[64][64 + 1];
    __shared__ uint32_t qL[64][5];

    const int tid = threadIdx.x;
    const int nchunk = blockIdx.x;
    const int h = blockIdx.y;
    const int be = blockIdx.z;
    const int d_own = tid >> 2;
    const int nw_own = tid & 3;

    float mem[32];
#pragma unroll
    for (int i = 0; i < 32; ++i) mem[i] = 0.0f;

    for (int t = 0; t < TT; ++t) {
        const int b = t * BE + be;
        const size_t base_row = (size_t)(b * CC + h * GD);

        for (int i = tid; i < 64 * NW; i += 256) {
            int r = i >> 4;
            int w = i & (NW - 1);
            kL[r][w] = kp[(base_row + r) * NW + w];
            vL[r][w] = vp[(base_row + r) * NW + w];
        }
        {
            int r = tid >> 2;
            int w = tid & 3;
            qL[r][w] = qp[(base_row + r) * NW + nchunk * 4 + w];
        }
        __syncthreads();

        for (int e = tid; e < 64 * 64; e += 256) {
            int d = e >> 6;
            int dp = e & 63;
            int s = 0;
#pragma unroll
            for (int w = 0; w < NW; ++w) s += __popc(vL[d][w] & kL[dp][w]);
            Msh[d][dp] = (float)s;
        }
        __syncthreads();

        float acc[32];
#pragma unroll
        for (int i = 0; i < 32; ++i) acc[i] = 0.0f;

        for (int dp = 0; dp < 64; ++dp) {
            float Mv = Msh[d_own][dp];
            uint32_t w = qL[dp][nw_own];
#pragma unroll
            for (int b2 = 0; b2 < 32; ++b2) {
                acc[b2] += ((w >> b2) & 1u) ? Mv : 0.0f;
            }
        }

        uint32_t sw = 0;
#pragma unroll
        for (int b2 = 0; b2 < 32; ++b2) {
            float m2 = mem[b2] * TAU + SCALE * acc[b2];
            bool s = m2 > THRESH;
            sw |= (s ? 1u : 0u) << b2;
            mem[b2] = s ? 0.0f : m2;
        }
        s3p[(base_row + d_own) * NW + nchunk * 4 + nw_own] = sw;
        __syncthreads();
    }
}

// ---------------------------------------------------------------------------
// Kernel 3: projection conv + BN -> fp32 out. Same pipeline as kernel 1.
// Grid (NN/128, CC/64, BB).
// ---------------------------------------------------------------------------
__global__ __launch_bounds__(256) void proj_kernel(
    const uint32_t* __restrict__ s3p,          // [BB*CC, NW] packed
    const float* __restrict__ W,               // [CC, CC]
    const float* __restrict__ bn_g,
    const float* __restrict__ bn_b,
    const float* __restrict__ bn_m,
    const float* __restrict__ bn_v,
    float* __restrict__ out)                   // [BB, CC, NN]
{
    __shared__ float Xs[2][16][132];
    __shared__ float Ws_s[2][16][68];

    const int tid = threadIdx.x;
    const int tx = tid & 15;
    const int ty = tid >> 4;
    const int n0 = blockIdx.x * 128;
    const int c0 = blockIdx.y * 64;
    const int b = blockIdx.z;

    float inv_c[4], add_c[4];
#pragma unroll
    for (int i = 0; i < 4; ++i) {
        int c = c0 + 4 * ty + i;
        float g = bn_g[3 * CC + c];
        float bt = bn_b[3 * CC + c];
        float m = bn_m[3 * CC + c];
        float v = bn_v[3 * CC + c];
        float inv = g / sqrtf(v + EPS);
        inv_c[i] = inv;
        add_c[i] = bt - m * inv;
    }

    const int xkk0 = tid >> 5;
    const int xcf0 = tid & 31;
    const int xkk1 = (tid + 256) >> 5;
    const int xcf1 = (tid + 256) & 31;
    const int wr = tid >> 2;
    const int wkw = tid & 3;

    float acc[4][8];
#pragma unroll
    for (int i = 0; i < 4; ++i)
#pragma unroll
        for (int j = 0; j < 8; ++j) acc[i][j] = 0.0f;

    auto ldspk = [&](int k0, int kk, int colf) -> uint32_t {
        return s3p[(size_t)(b * CC + k0 + kk) * NW + (n0 >> 5) + (colf >> 3)];
    };
    auto expand = [&](uint32_t word, int colf) -> float4 {
        int sh = 4 * (colf & 7);
        float4 xv;
        xv.x = (float)((word >> (sh + 0)) & 1u);
        xv.y = (float)((word >> (sh + 1)) & 1u);
        xv.z = (float)((word >> (sh + 2)) & 1u);
        xv.w = (float)((word >> (sh + 3)) & 1u);
        return xv;
    };

    // prologue k0=0 -> buf0
    uint32_t w0 = ldspk(0, xkk0, xcf0);
    uint32_t w1 = ldspk(0, xkk1, xcf1);
    float4 pw = *(const float4*)&W[(size_t)(c0 + wr) * CC + 0 + 4 * wkw];
    *(float4*)&Xs[0][xkk0][4 * xcf0] = expand(w0, xcf0);
    *(float4*)&Xs[0][xkk1][4 * xcf1] = expand(w1, xcf1);
    Ws_s[0][4 * wkw + 0][wr] = pw.x;
    Ws_s[0][4 * wkw + 1][wr] = pw.y;
    Ws_s[0][4 * wkw + 2][wr] = pw.z;
    Ws_s[0][4 * wkw + 3][wr] = pw.w;
    __syncthreads();
    w0 = ldspk(16, xkk0, xcf0);
    w1 = ldspk(16, xkk1, xcf1);
    pw = *(const float4*)&W[(size_t)(c0 + wr) * CC + 16 + 4 * wkw];

    int cur = 0;
    for (int k0 = 0; k0 < CC; k0 += 16) {
#pragma unroll
        for (int kk = 0; kk < 16; ++kk) {
            float4 av  = *(float4*)&Ws_s[cur][kk][4 * ty];
            float4 xlo = *(float4*)&Xs[cur][kk][4 * tx];
            float4 xhi = *(float4*)&Xs[cur][kk][64 + 4 * tx];
            const float a[4] = {av.x, av.y, av.z, av.w};
            const float xl[4] = {xlo.x, xlo.y, xlo.z, xlo.w};
            const float xh[4] = {xhi.x, xhi.y, xhi.z, xhi.w};
#pragma unroll
            for (int i = 0; i < 4; ++i) {
#pragma unroll
                for (int j = 0; j < 4; ++j) {
                    acc[i][j] += a[i] * xl[j];
                    acc[i][4 + j] += a[i] * xh[j];
                }
            }
        }
        if (k0 + 16 < CC) {
            int nxt = cur ^ 1;
            *(float4*)&Xs[nxt][xkk0][4 * xcf0] = expand(w0, xcf0);
            *(float4*)&Xs[nxt][xkk1][4 * xcf1] = expand(w1, xcf1);
            Ws_s[nxt][4 * wkw + 0][wr] = pw.x;
            Ws_s[nxt][4 * wkw + 1][wr] = pw.y;
            Ws_s[nxt][4 * wkw + 2][wr] = pw.z;
            Ws_s[nxt][4 * wkw + 3][wr] = pw.w;
            __syncthreads();
            cur = nxt;
            if (k0 + 32 < CC) {
                int kn = k0 + 32;
                w0 = ldspk(kn, xkk0, xcf0);
                w1 = ldspk(kn, xkk1, xcf1);
                pw = *(const float4*)&W[(size_t)(c0 + wr) * CC + kn + 4 * wkw];
            }
        }
    }

    float* ob = out + (size_t)b * CC * NN;
#pragma unroll
    for (int i = 0; i < 4; ++i) {
        int c = c0 + 4 * ty + i;
        float4 lo, hi;
        lo.x = acc[i][0] * inv_c[i] + add_c[i];
        lo.y = acc[i][1] * inv_c[i] + add_c[i];
        lo.z = acc[i][2] * inv_c[i] + add_c[i];
        lo.w = acc[i][3] * inv_c[i] + add_c[i];
        hi.x = acc[i][4] * inv_c[i] + add_c[i];
        hi.y = acc[i][5] * inv_c[i] + add_c[i];
        hi.z = acc[i][6] * inv_c[i] + add_c[i];
        hi.w = acc[i][7] * inv_c[i] + add_c[i];
        *(float4*)&ob[(size_t)c * NN + n0 + 4 * tx] = lo;
        *(float4*)&ob[(size_t)c * NN + n0 + 64 + 4 * tx] = hi;
    }
}

// ---------------------------------------------------------------------------
extern "C" void kernel_launch(void* const* d_in, const int* in_sizes, int n_in,
                              void* d_out, int out_size, void* d_ws, size_t ws_size,
                              hipStream_t stream) {
    const float* x     = (const float*)d_in[0];
    const float* wq    = (const float*)d_in[1];
    const float* wk    = (const float*)d_in[2];
    const float* wv    = (const float*)d_in[3];
    const float* wproj = (const float*)d_in[4];
    const float* bng   = (const float*)d_in[5];
    const float* bnb   = (const float*)d_in[6];
    const float* bnm   = (const float*)d_in[7];
    const float* bnv   = (const float*)d_in[8];

    const size_t PK = (size_t)BB * CC * NW;            // 2 MiB each
    uint32_t* qp  = (uint32_t*)d_ws;
    uint32_t* kp  = qp + PK;
    uint32_t* vp  = kp + PK;
    uint32_t* s3p = vp + PK;                           // total 8 MiB

    dim3 gconv(NN / 128, CC / 64, 3 * BE);             // z = w*16 + be
    conv_bn_lif_kernel<<<gconv, 256, 0, stream>>>(x, wq, wk, wv, bng, bnb, bnm, bnv,
                                                  qp, kp, vp);

    dim3 gattn(4, NH, BE);
    attn_lif_kernel<<<gattn, 256, 0, stream>>>(qp, kp, vp, s3p);

    dim3 gproj(NN / 128, CC / 64, BB);
    proj_kernel<<<gproj, 256, 0, stream>>>(s3p, wproj, bng, bnb, bnm, bnv, (float*)d_out);
}